// Round 8
// baseline (198.335 us; speedup 1.0000x reference)
//
#include <hip/hip_runtime.h>
#include <math.h>

// Problem constants (fixed by the reference)
namespace {
constexpr int IN_DIMc = 159;   // L1*(DIM+1)+L2
constexpr int MDIMc   = 93;    // L2*DIM
constexpr int MATELc  = 2976;  // banded tril nnz
constexpr int ROWS    = MDIMc + MATELc;  // 3069
constexpr int SIGDIMc = 340;   // 4+16+64+256
constexpr int NCLSc   = 10;
}

// Packed-FP32 helpers. R17: native IR, NOT inline asm (asm forced operands
// into fresh aligned VGPR pairs -> mov glue). R21: the kernel is LDS-pipe
// THROUGHPUT bound (per-op ~6-12cy x 32 resident waves explains the whole
// 53.6us wall; unroll-4 null in R7 confirmed not-latency). So selects move
// off the LDS pipe via one-hot masked pk-fma (exact: x*1.0=x, +0 exact).
typedef float f2v __attribute__((ext_vector_type(2)));
__device__ __forceinline__ f2v pk_fma(f2v a, f2v b, f2v c) {
#if __has_builtin(__builtin_elementwise_fma)
  return __builtin_elementwise_fma(a, b, c);
#else
  f2v d; d.x = fmaf(a.x, b.x, c.x); d.y = fmaf(a.y, b.y, c.y); return d;
#endif
}
__device__ __forceinline__ f2v pk_mul(f2v a, f2v b) { return a * b; }
__device__ __forceinline__ f2v pk_add(f2v a, f2v b) { return a + b; }

// Device-global scratch (static: no ws_size assumption).
__device__ float g_mc[256 * 3072];      // [B][3069] mean|cov
__device__ float g_logits[256 * NCLSc]; // per-batch logit accumulators
__device__ int   g_cnt[256];            // per-batch arrival tickets

// --------------------------------------------------------------------------
// Kernel 1: g_mc[b][r] = dot(x[b,:159], Wcat[r,:159]) + bcat[r]
// R19 geometry. Frozen (total - path_sig ~= 92us constant -> not a lever).
// --------------------------------------------------------------------------
__global__ __launch_bounds__(256) void gemm_mc(
    const float* __restrict__ x, const float* __restrict__ Wm,
    const float* __restrict__ bm, const float* __restrict__ Wc,
    const float* __restrict__ bc)
{
  __shared__ __align__(16) float wls[32 * 164];  // [row][164], cols 159..163 = 0
  __shared__ __align__(16) float xls[32 * 160];  // [batch][160]
  const int t  = threadIdx.x;
  const int r0 = blockIdx.x * 32;
  const int b0 = blockIdx.y * 32;

  for (int idx = t; idx < 32 * 164; idx += 256) {
    int rr = idx / 164, ii = idx - rr * 164;
    int r = r0 + rr;
    float v = 0.0f;
    if (ii < IN_DIMc) {
      if (r < MDIMc)      v = Wm[r * IN_DIMc + ii];
      else if (r < ROWS)  v = Wc[(r - MDIMc) * IN_DIMc + ii];
    }
    wls[idx] = v;
  }
  // x tile: global range [b0*159, (b0+32)*159) is contiguous -> coalesced.
  for (int idx = t; idx < 32 * IN_DIMc; idx += 256) {
    int bb = idx / IN_DIMc, ii = idx - bb * IN_DIMc;
    xls[bb * 160 + ii] = x[b0 * IN_DIMc + idx];
  }
  __syncthreads();

  const int rl = t & 31;    // row within tile
  const int bg = t >> 5;    // 8 groups x 4 batches
  const float* xb = xls + (bg * 4) * 160;

  float acc[4] = {0, 0, 0, 0};
  const float4* wls4 = (const float4*)wls;
  for (int c = 0; c < 39; ++c) {          // i = 0..155
    float4 wv = wls4[rl * 41 + c];
#pragma unroll
    for (int j = 0; j < 4; ++j) {
      float4 xv = *(const float4*)(xb + j * 160 + c * 4);  // broadcast b128
      acc[j] = fmaf(wv.x, xv.x, acc[j]);
      acc[j] = fmaf(wv.y, xv.y, acc[j]);
      acc[j] = fmaf(wv.z, xv.z, acc[j]);
      acc[j] = fmaf(wv.w, xv.w, acc[j]);
    }
  }
  for (int i = 156; i < IN_DIMc; ++i) {   // epilogue
    float wv = wls[rl * 164 + i];
#pragma unroll
    for (int j = 0; j < 4; ++j) acc[j] = fmaf(wv, xb[j * 160 + i], acc[j]);
  }

  const int r = r0 + rl;
  if (r < ROWS) {
    float bias = (r < MDIMc) ? bm[r] : bc[r - MDIMc];
#pragma unroll
    for (int j = 0; j < 4; ++j)
      g_mc[(size_t)(b0 + bg * 4 + j) * ROWS + r] = acc[j] + bias;
  }
}

// --------------------------------------------------------------------------
// Kernel 2: 512 blocks (2 per batch), 1024 threads = 16 waves.
// Block bx handles batch b = bx>>1, paths [h*32, h*32+32) with h = bx&1.
// ~45.7 KB LDS -> 2 blocks/CU -> 32 waves/CU (HW cap).
// R21 ledger (per-CU LDS pipe, 32 waves): P2 was 35us (5 LDS ops/iter),
// P1 ~15us, norm/P3 ~4us -> LDS-throughput bound everywhere.
//  P0: stage x, mean, cov (R19 latency-overlapped), 32 eps columns.
//  P1: newV = banded-tril(cov) @ eps + mean (R19 base-recurrence).
//  P2 (R21): 2 uniform b128 reads ONLY; component selects via one-hot
//      masked pk-fma (12 loop-invariant f2v masks; 12 pk ops/iter replace
//      3 b64 LDS reads = 18 pipe-cy). New per-iter-round ledger: LDS
//      2x12x32 = 768cy vs VALU ~30x2x8 = 480cy -> P2 ~20us (was 35).
//      Numerically exact (x*1.0, +0.0 exact; same stored values).
//  P3: reduce 16 waves -> sig[340]; waves 0..9 atomicAdd partial logits;
//      ticket on g_cnt[b]; second block's wave 0 finishes log_softmax.
// Lane layout: l = a*16+b*4+c. Lane holds S4[4l..4l+3], S3[l],
// S2[l>>2] (x4 replicated), S1[l>>4] (x16 replicated).
// --------------------------------------------------------------------------
__global__ __launch_bounds__(1024, 8) void path_sig(
    const float* __restrict__ x, const float* __restrict__ eps,
    const float* __restrict__ Wf, const float* __restrict__ bf,
    float* __restrict__ out)
{
  constexpr int OFF_XS   = 0;
  constexpr int OFF_NEWV = 160;
  constexpr int OFF_SIG  = 160;     // aliases dead newV
  constexpr int OFF_DX   = 3232;
  constexpr int OFF_EPS  = 3232;
  constexpr int OFF_MEAN = 6208;
  constexpr int OFF_COV  = 6304;    // 16B-aligned; dead before dx build
  constexpr int OFF_PART = 3232;
  __shared__ __align__(16) float smem[11424];
  __shared__ int finFlag;
  float* xsm   = smem + OFF_XS;
  float* newVL = smem + OFF_NEWV;
  float* epsL  = smem + OFF_EPS;
  float* meanL = smem + OFF_MEAN;
  float* covL  = smem + OFF_COV;
  float* sigL  = smem + OFF_SIG;

  const int t  = threadIdx.x;
  const int bx = blockIdx.x;
  const int b  = bx >> 1;
  const int h  = bx & 1;

  // ---- P0: stage inputs ----
  if (t < IN_DIMc) xsm[t] = x[b * IN_DIMc + t];
  else if (t >= 512 && t < 512 + MDIMc)
    meanL[t - 512] = g_mc[(size_t)b * ROWS + (t - 512)];
  {
    // this block's 32 eps columns: 93 rows x 8 float4
    const float4* ep4 = (const float4*)eps;
    float4* el4 = (float4*)epsL;
    if (t < 93 * 8) {
      int r = t >> 3, c4 = t & 7;
      el4[r * 8 + c4] = ep4[((size_t)b * 93 + r) * 16 + h * 8 + c4];
    }
  }
  {
    // cov[b] -> LDS: 3 rounds, loads issued before writes (latency overlap).
    // Unconditional loads stay inside g_mc even at b=255; last write guarded.
    const float* covG = g_mc + (size_t)b * ROWS + MDIMc;
    float c0 = covG[t];
    float c1 = covG[t + 1024];
    float c2 = covG[t + 2048];
    covL[t] = c0;
    covL[t + 1024] = c1;
    if (t + 2048 < MATELc) covL[t + 2048] = c2;
  }
  __syncthreads();

  // ---- P1: newV[r][col] for the block's 32 columns (cov from LDS) ----
  const int l = t & 63;
  const int w = t >> 6;           // wave id 0..15
  {
    const int col = l & 31;
    const int h2  = l >> 5;
    const float* ecol = epsL + col;
    for (int r = (w << 1) | h2; r < MDIMc; r += 32) {
      const int X  = r / 3;
      const int tr = r - X * 3;
      float acc = meanL[r];
      const int tb = (tr * (tr + 1)) >> 1;
      // base(y) = 6*(31*(X-y) - (X-y)(X-y-1)/2) + 6y + tb
      // recurrence: base(y+1) = base(y) + 6*(X-y) - 186
      int base = 6 * (31 * X - ((X * (X - 1)) >> 1)) + tb;
      int dlt  = 6 * X - 186;
      int ey   = 0;                 // = (y*3)*32
      for (int y = 0; y <= X; ++y) {
        acc = fmaf(covL[base], ecol[ey], acc);
        if (tr >= 1) acc = fmaf(covL[base + 1], ecol[ey + 32], acc);
        if (tr == 2) acc = fmaf(covL[base + 2], ecol[ey + 64], acc);
        base += dlt; dlt -= 6; ey += 96;
      }
      newVL[r * 33 + col] = acc;
    }
  }
  __syncthreads();   // newV/xsm stable; eps/mean/cov dead -> dx may now alias

  // ---- P2: dual-path signatures (barrier-free; dx is wave-private) ----
  const int la = l >> 4, lb = (l >> 2) & 3, lc = l & 3;
  float* dxb = smem + OFF_DX + w * 512;     // 62 interleaved 32B slots
  const float inv6 = 1.0f / 6.0f, inv24 = 1.0f / 24.0f;

  const int kk0 = w << 1, kk1 = kk0 | 1;    // this wave's two paths
  // build increment buffers, path-interleaved; dx[i]=p[i+1]-p[i]
  if (l < 62) {
    const int m = l >> 1;
    float4 dv0, dv1;
    if ((l & 1) == 0) {
      float x0 = xsm[3 * m], x1 = xsm[3 * m + 1], x2 = xsm[3 * m + 2];
      float tw = xsm[128 + m] - xsm[96 + m];
      dv0.x = newVL[(3 * m) * 33 + kk0]     - x0;
      dv0.y = newVL[(3 * m + 1) * 33 + kk0] - x1;
      dv0.z = newVL[(3 * m + 2) * 33 + kk0] - x2;
      dv0.w = tw;
      dv1.x = newVL[(3 * m) * 33 + kk1]     - x0;
      dv1.y = newVL[(3 * m + 1) * 33 + kk1] - x1;
      dv1.z = newVL[(3 * m + 2) * 33 + kk1] - x2;
      dv1.w = tw;
    } else {
      float x0 = xsm[3 * m + 3], x1 = xsm[3 * m + 4], x2 = xsm[3 * m + 5];
      float tw = xsm[96 + m + 1] - xsm[128 + m];
      dv0.x = x0 - newVL[(3 * m) * 33 + kk0];
      dv0.y = x1 - newVL[(3 * m + 1) * 33 + kk0];
      dv0.z = x2 - newVL[(3 * m + 2) * 33 + kk0];
      dv0.w = tw;
      dv1.x = x0 - newVL[(3 * m) * 33 + kk1];
      dv1.y = x1 - newVL[(3 * m + 1) * 33 + kk1];
      dv1.z = x2 - newVL[(3 * m + 2) * 33 + kk1];
      dv1.w = tw;
    }
    *(float4*)(dxb + l * 8)     = make_float4(dv0.x, dv1.x, dv0.y, dv1.y);
    *(float4*)(dxb + l * 8 + 4) = make_float4(dv0.z, dv1.z, dv0.w, dv1.w);
  }
  // no __syncthreads: dxb is wave-private (same-wave lgkmcnt ordering)

  // one-hot component-select masks (loop-invariant; exact 1.0/0.0)
  const float a0 = (la == 0) ? 1.f : 0.f, a1 = (la == 1) ? 1.f : 0.f;
  const float a2 = (la == 2) ? 1.f : 0.f, a3 = (la == 3) ? 1.f : 0.f;
  const float b0m = (lb == 0) ? 1.f : 0.f, b1m = (lb == 1) ? 1.f : 0.f;
  const float b2m = (lb == 2) ? 1.f : 0.f, b3m = (lb == 3) ? 1.f : 0.f;
  const float c0m = (lc == 0) ? 1.f : 0.f, c1m = (lc == 1) ? 1.f : 0.f;
  const float c2m = (lc == 2) ? 1.f : 0.f, c3m = (lc == 3) ? 1.f : 0.f;
  const f2v ma0 = {a0, a0}, ma1 = {a1, a1}, ma2 = {a2, a2}, ma3 = {a3, a3};
  const f2v mb0 = {b0m, b0m}, mb1 = {b1m, b1m}, mb2 = {b2m, b2m}, mb3 = {b3m, b3m};
  const f2v mc0 = {c0m, c0m}, mc1 = {c1m, c1m}, mc2 = {c2m, c2m}, mc3 = {c3m, c3m};

  f2v p1a = {0.f, 0.f}, p2o = {0.f, 0.f}, p3 = {0.f, 0.f};
  f2v p4x = {0.f, 0.f}, p4y = {0.f, 0.f}, p4z = {0.f, 0.f}, p4w = {0.f, 0.f};
  const f2v kH = {0.5f, 0.5f}, k6 = {inv6, inv6}, k24 = {inv24, inv24};
  const float4* dx4 = (const float4*)dxb;
#pragma unroll 4
  for (int i = 0; i < 62; ++i) {
    float4 pAv = dx4[2 * i];          // uniform b128: (d0.x,d1.x,d0.y,d1.y)
    float4 pBv = dx4[2 * i + 1];      // uniform b128: (d0.z,d1.z,d0.w,d1.w)
    f2v px = {pAv.x, pAv.y}, py = {pAv.z, pAv.w};
    f2v pz = {pBv.x, pBv.y}, pw = {pBv.z, pBv.w};
    // in-register one-hot selects (4 pk ops each; zero LDS-pipe traffic;
    // exact: one mask is 1.0, rest 0.0 -> value passes through unchanged)
    f2v dxa  = pk_fma(pw, ma3, pk_fma(pz, ma2, pk_fma(py, ma1, pk_mul(px, ma0))));
    f2v dxbv = pk_fma(pw, mb3, pk_fma(pz, mb2, pk_fma(py, mb1, pk_mul(px, mb0))));
    f2v dxc  = pk_fma(pw, mc3, pk_fma(pz, mc2, pk_fma(py, mc1, pk_mul(px, mc0))));
    // packed two-path Chen step (identical formula/order to scalar version)
    f2v bcv  = pk_mul(dxbv, dxc);
    f2v i1   = pk_fma(p1a, k6, pk_mul(dxa, k24));
    f2v i2   = pk_fma(p1a, kH, pk_mul(dxa, k6));
    f2v u    = pk_mul(p2o, dxc);
    f2v cB   = pk_fma(u, kH, p3);
    f2v coef = pk_fma(i1, bcv, cB);
    p4x = pk_fma(coef, px, p4x);
    p4y = pk_fma(coef, py, p4y);
    p4z = pk_fma(coef, pz, p4z);
    p4w = pk_fma(coef, pw, p4w);
    p3  = pk_fma(i2, bcv, pk_add(u, p3));
    p2o = pk_fma(dxbv, pk_fma(dxa, kH, p1a), p2o);
    p1a = pk_add(p1a, dxa);
  }
  const float s1a0 = p1a.x, s2o0 = p2o.x, s30 = p3.x;
  const float s1a1 = p1a.y, s2o1 = p2o.y, s31 = p3.y;
  const float4 s40 = make_float4(p4x.x, p4y.x, p4z.x, p4w.x);
  const float4 s41 = make_float4(p4x.y, p4y.y, p4z.y, p4w.y);

  // ---- normalization + accumulate (path 0 first: same order as before) ----
  float acc1 = 0.f, acc2 = 0.f, acc3 = 0.f;
  float4 acc4 = make_float4(0.f, 0.f, 0.f, 0.f);
#pragma unroll 1
  for (int j = 0; j < 2; ++j) {
    float s1a = j ? s1a1 : s1a0;
    float s2o = j ? s2o1 : s2o0;
    float s3  = j ? s31 : s30;
    float4 s4 = j ? s41 : s40;
    float c4 = s4.x * s4.x + s4.y * s4.y + s4.z * s4.z + s4.w * s4.w;
    float c3v = s3 * s3;
    float c2v = s2o * s2o;    // x4-replicated: xor4..32 sums 16 distinct
    float c1v = s1a * s1a;    // x16-replicated: xor16,32 sums 4 distinct
#pragma unroll
    for (int off = 1; off < 64; off <<= 1) {
      c3v += __shfl_xor(c3v, off);
      c4  += __shfl_xor(c4, off);
    }
    c2v += __shfl_xor(c2v, 4);
    c2v += __shfl_xor(c2v, 8);
    c2v += __shfl_xor(c2v, 16);
    c2v += __shfl_xor(c2v, 32);
    c1v += __shfl_xor(c1v, 16);
    c1v += __shfl_xor(c1v, 32);
    float norm2 = 1.f + c1v + c2v + c3v + c4;
    float lam, lam2;
    if (norm2 <= 4.0f) {          // wave-uniform: phi(x)=x -> lam -> 1
      lam = 1.0f; lam2 = 1.0f;
    } else {
      // bisection on the quartic in m2 = lam^2 (25 iters ~ 3e-8 interval)
      float psi = 8.0f - 16.0f / norm2;
      float lo = 0.f, hi = 1.f;
#pragma unroll
      for (int it = 0; it < 25; ++it) {
        float mid = 0.5f * (lo + hi);
        float m2 = mid * mid;
        float val =
            fmaf(m2, fmaf(m2, fmaf(m2, fmaf(m2, c4, c3v), c2v), c1v), 1.f);
        bool pos = val > psi;
        hi = pos ? mid : hi;
        lo = pos ? lo : mid;
      }
      lam = 0.5f * (lo + hi);
      lam2 = lam * lam;
    }
    const float lam3 = lam2 * lam, lam4 = lam2 * lam2;
    acc1 = fmaf(s1a, lam, acc1);
    acc2 = fmaf(s2o, lam2, acc2);
    acc3 = fmaf(s3, lam3, acc3);
    acc4.x = fmaf(s4.x, lam4, acc4.x);
    acc4.y = fmaf(s4.y, lam4, acc4.y);
    acc4.z = fmaf(s4.z, lam4, acc4.z);
    acc4.w = fmaf(s4.w, lam4, acc4.w);
  }

  // ---- P3: barrier (part aliases dx), reduce waves -> sig in LDS ----
  __syncthreads();   // all waves done with dx before part overwrites it
  {
    float* part = smem + OFF_PART + w * SIGDIMc;
    if ((l & 15) == 0) part[l >> 4] = acc1;        // S1[0..3]
    if (lc == 0)       part[4 + (l >> 2)] = acc2;  // S2[0..15]
    part[20 + l] = acc3;                           // S3[0..63]
    *(float4*)(part + 84 + 4 * l) = acc4;          // S4[0..255]
  }
  __syncthreads();

  if (t < SIGDIMc) {
    float s = 0.f;
#pragma unroll
    for (int ww = 0; ww < 16; ++ww) s += smem[OFF_PART + ww * SIGDIMc + t];
    sigL[t] = s * (1.0f / 64.0f);     // this half-batch's sig contribution
  }
  __syncthreads();

  // ---- partial logits (linear in sig): waves 0..9, one class each ----
  if (w < NCLSc) {
    float s = 0.f;
    for (int jj = l; jj < SIGDIMc; jj += 64)
      s = fmaf(sigL[jj], Wf[w * SIGDIMc + jj], s);
#pragma unroll
    for (int off = 1; off < 64; off <<= 1) s += __shfl_xor(s, off);
    if (l == 0) atomicAdd(&g_logits[b * NCLSc + w], s);   // device-scope
  }
  __syncthreads();   // barrier drain (vmcnt 0) -> logit atomics complete

  // ---- last-arriving block finishes the batch (fence-free) ----
  if (t == 0) finFlag = atomicAdd(&g_cnt[b], 1);
  __syncthreads();
  if (finFlag == 1 && w == 0) {
    float lg = -1e30f;
    if (l < NCLSc)   // coherent read of the completed sum
      lg = atomicAdd(&g_logits[b * NCLSc + l], 0.0f) + bf[l];
    float mx = lg;
#pragma unroll
    for (int i2 = 0; i2 < NCLSc; ++i2) mx = fmaxf(mx, __shfl(lg, i2));
    float se = 0.f;
#pragma unroll
    for (int i2 = 0; i2 < NCLSc; ++i2) se += expf(__shfl(lg, i2) - mx);
    if (l < NCLSc) {
      out[b * NCLSc + l] = lg - mx - logf(se);
      atomicExch(&g_logits[b * NCLSc + l], 0.0f);  // coherent reset
    }
    if (l == 0) atomicExch(&g_cnt[b], 0);          // coherent reset
  }
}

extern "C" void kernel_launch(void* const* d_in, const int* in_sizes, int n_in,
                              void* d_out, int out_size, void* d_ws, size_t ws_size,
                              hipStream_t stream) {
  (void)in_sizes; (void)n_in; (void)out_size; (void)d_ws; (void)ws_size;
  const float* x   = (const float*)d_in[0];
  const float* Wm  = (const float*)d_in[1];
  const float* bm  = (const float*)d_in[2];
  const float* Wc  = (const float*)d_in[3];
  const float* bcv = (const float*)d_in[4];
  const float* Wf  = (const float*)d_in[5];
  const float* bf  = (const float*)d_in[6];
  const float* eps = (const float*)d_in[7];
  // d_in[8]/d_in[9] (x_idx/y_idx) are compile-time deterministic; hard-coded.
  float* out = (float*)d_out;

  gemm_mc<<<dim3(96, 8), 256, 0, stream>>>(x, Wm, bm, Wc, bcv);
  path_sig<<<dim3(512), 1024, 0, stream>>>(x, eps, Wf, bf, out);
}

// Round 9
// 152.697 us; speedup vs baseline: 1.2989x; 1.2989x over previous
//
#include <hip/hip_runtime.h>
#include <math.h>

// Problem constants (fixed by the reference)
namespace {
constexpr int IN_DIMc = 159;   // L1*(DIM+1)+L2
constexpr int MDIMc   = 93;    // L2*DIM
constexpr int MATELc  = 2976;  // banded tril nnz
constexpr int ROWS    = MDIMc + MATELc;  // 3069
constexpr int SIGDIMc = 340;   // 4+16+64+256
constexpr int NCLSc   = 10;
}

// Packed-FP32 helpers. R17: native IR, NOT inline asm. R19/R21/R22: VALU
// cndmask / one-hot-mask selects regressed 3x (R2,R5,R8 -- R8 spilled to
// scratch under the 64-VGPR cap); LDS b64 selects are the right structure.
typedef float f2v __attribute__((ext_vector_type(2)));
__device__ __forceinline__ f2v pk_fma(f2v a, f2v b, f2v c) {
#if __has_builtin(__builtin_elementwise_fma)
  return __builtin_elementwise_fma(a, b, c);
#else
  f2v d; d.x = fmaf(a.x, b.x, c.x); d.y = fmaf(a.y, b.y, c.y); return d;
#endif
}
__device__ __forceinline__ f2v pk_mul(f2v a, f2v b) { return a * b; }
__device__ __forceinline__ f2v pk_add(f2v a, f2v b) { return a + b; }

// Device-global scratch (static: no ws_size assumption).
__device__ float g_mc[256 * 3072];      // [B][3069] mean|cov
__device__ float g_logits[256 * NCLSc]; // per-batch logit accumulators
__device__ int   g_cnt[256];            // per-batch arrival tickets

// --------------------------------------------------------------------------
// Kernel 1: g_mc[b][r] = dot(x[b,:159], Wcat[r,:159]) + bcat[r]
// R19 geometry. Frozen (total - path_sig ~= 92us constant -> not a lever).
// --------------------------------------------------------------------------
__global__ __launch_bounds__(256) void gemm_mc(
    const float* __restrict__ x, const float* __restrict__ Wm,
    const float* __restrict__ bm, const float* __restrict__ Wc,
    const float* __restrict__ bc)
{
  __shared__ __align__(16) float wls[32 * 164];  // [row][164], cols 159..163 = 0
  __shared__ __align__(16) float xls[32 * 160];  // [batch][160]
  const int t  = threadIdx.x;
  const int r0 = blockIdx.x * 32;
  const int b0 = blockIdx.y * 32;

  for (int idx = t; idx < 32 * 164; idx += 256) {
    int rr = idx / 164, ii = idx - rr * 164;
    int r = r0 + rr;
    float v = 0.0f;
    if (ii < IN_DIMc) {
      if (r < MDIMc)      v = Wm[r * IN_DIMc + ii];
      else if (r < ROWS)  v = Wc[(r - MDIMc) * IN_DIMc + ii];
    }
    wls[idx] = v;
  }
  // x tile: global range [b0*159, (b0+32)*159) is contiguous -> coalesced.
  for (int idx = t; idx < 32 * IN_DIMc; idx += 256) {
    int bb = idx / IN_DIMc, ii = idx - bb * IN_DIMc;
    xls[bb * 160 + ii] = x[b0 * IN_DIMc + idx];
  }
  __syncthreads();

  const int rl = t & 31;    // row within tile
  const int bg = t >> 5;    // 8 groups x 4 batches
  const float* xb = xls + (bg * 4) * 160;

  float acc[4] = {0, 0, 0, 0};
  const float4* wls4 = (const float4*)wls;
  for (int c = 0; c < 39; ++c) {          // i = 0..155
    float4 wv = wls4[rl * 41 + c];
#pragma unroll
    for (int j = 0; j < 4; ++j) {
      float4 xv = *(const float4*)(xb + j * 160 + c * 4);  // broadcast b128
      acc[j] = fmaf(wv.x, xv.x, acc[j]);
      acc[j] = fmaf(wv.y, xv.y, acc[j]);
      acc[j] = fmaf(wv.z, xv.z, acc[j]);
      acc[j] = fmaf(wv.w, xv.w, acc[j]);
    }
  }
  for (int i = 156; i < IN_DIMc; ++i) {   // epilogue
    float wv = wls[rl * 164 + i];
#pragma unroll
    for (int j = 0; j < 4; ++j) acc[j] = fmaf(wv, xb[j * 160 + i], acc[j]);
  }

  const int r = r0 + rl;
  if (r < ROWS) {
    float bias = (r < MDIMc) ? bm[r] : bc[r - MDIMc];
#pragma unroll
    for (int j = 0; j < 4; ++j)
      g_mc[(size_t)(b0 + bg * 4 + j) * ROWS + r] = acc[j] + bias;
  }
}

// --------------------------------------------------------------------------
// Kernel 2: 512 blocks (2 per batch), 1024 threads = 16 waves.
// Block bx handles batch b = bx>>1, paths [h*32, h*32+32) with h = bx&1.
// ~45.7 KB LDS -> 2 blocks/CU -> 32 waves/CU (HW cap).
// R21 ledger (per-CU LDS pipe, 32 waves): kernel is LDS-throughput bound
// (P2 35us at 42cy/iter/wave, P1 ~15us, norm/misc ~4us = measured 53.6).
//  P0: stage x, mean, cov (R19 latency-overlapped), 32 eps columns.
//  P1: newV = banded-tril(cov) @ eps + mean (R19 base-recurrence).
//  P2 (R22): the 2 wave-UNIFORM b128 reads (24 of 42 LDS cy/iter) move to
//      v_readlane_b32: the dx build already computes slot l in lane l, so
//      retain the 8 floats in VGPRs (lane i holds slot i) and fetch with 8
//      readlanes/iter (loop counter is wave-uniform -> SGPR lane index;
//      results stay in SGPRs; each pk op has <=1 SGPR-pair source -> legal).
//      The 3 per-lane b64 LDS selects stay (R4-proven; VALU selects
//      regressed 3x). LDS 42->18 cy/iter/wave -> P2 ~17-20us.
//      Same values, same op order -> bit-identical.
//  P3: reduce 16 waves -> sig[340]; waves 0..9 atomicAdd partial logits;
//      ticket on g_cnt[b]; second block's wave 0 finishes log_softmax.
// Lane layout: l = a*16+b*4+c. Lane holds S4[4l..4l+3], S3[l],
// S2[l>>2] (x4 replicated), S1[l>>4] (x16 replicated).
// --------------------------------------------------------------------------
__global__ __launch_bounds__(1024, 8) void path_sig(
    const float* __restrict__ x, const float* __restrict__ eps,
    const float* __restrict__ Wf, const float* __restrict__ bf,
    float* __restrict__ out)
{
  constexpr int OFF_XS   = 0;
  constexpr int OFF_NEWV = 160;
  constexpr int OFF_SIG  = 160;     // aliases dead newV
  constexpr int OFF_DX   = 3232;
  constexpr int OFF_EPS  = 3232;
  constexpr int OFF_MEAN = 6208;
  constexpr int OFF_COV  = 6304;    // 16B-aligned; dead before dx build
  constexpr int OFF_PART = 3232;
  __shared__ __align__(16) float smem[11424];
  __shared__ int finFlag;
  float* xsm   = smem + OFF_XS;
  float* newVL = smem + OFF_NEWV;
  float* epsL  = smem + OFF_EPS;
  float* meanL = smem + OFF_MEAN;
  float* covL  = smem + OFF_COV;
  float* sigL  = smem + OFF_SIG;

  const int t  = threadIdx.x;
  const int bx = blockIdx.x;
  const int b  = bx >> 1;
  const int h  = bx & 1;

  // ---- P0: stage inputs ----
  if (t < IN_DIMc) xsm[t] = x[b * IN_DIMc + t];
  else if (t >= 512 && t < 512 + MDIMc)
    meanL[t - 512] = g_mc[(size_t)b * ROWS + (t - 512)];
  {
    // this block's 32 eps columns: 93 rows x 8 float4
    const float4* ep4 = (const float4*)eps;
    float4* el4 = (float4*)epsL;
    if (t < 93 * 8) {
      int r = t >> 3, c4 = t & 7;
      el4[r * 8 + c4] = ep4[((size_t)b * 93 + r) * 16 + h * 8 + c4];
    }
  }
  {
    // cov[b] -> LDS: 3 rounds, loads issued before writes (latency overlap).
    // Unconditional loads stay inside g_mc even at b=255; last write guarded.
    const float* covG = g_mc + (size_t)b * ROWS + MDIMc;
    float c0 = covG[t];
    float c1 = covG[t + 1024];
    float c2 = covG[t + 2048];
    covL[t] = c0;
    covL[t + 1024] = c1;
    if (t + 2048 < MATELc) covL[t + 2048] = c2;
  }
  __syncthreads();

  // ---- P1: newV[r][col] for the block's 32 columns (cov from LDS) ----
  const int l = t & 63;
  const int w = t >> 6;           // wave id 0..15
  {
    const int col = l & 31;
    const int h2  = l >> 5;
    const float* ecol = epsL + col;
    for (int r = (w << 1) | h2; r < MDIMc; r += 32) {
      const int X  = r / 3;
      const int tr = r - X * 3;
      float acc = meanL[r];
      const int tb = (tr * (tr + 1)) >> 1;
      // base(y) = 6*(31*(X-y) - (X-y)(X-y-1)/2) + 6y + tb
      // recurrence: base(y+1) = base(y) + 6*(X-y) - 186
      int base = 6 * (31 * X - ((X * (X - 1)) >> 1)) + tb;
      int dlt  = 6 * X - 186;
      int ey   = 0;                 // = (y*3)*32
      for (int y = 0; y <= X; ++y) {
        acc = fmaf(covL[base], ecol[ey], acc);
        if (tr >= 1) acc = fmaf(covL[base + 1], ecol[ey + 32], acc);
        if (tr == 2) acc = fmaf(covL[base + 2], ecol[ey + 64], acc);
        base += dlt; dlt -= 6; ey += 96;
      }
      newVL[r * 33 + col] = acc;
    }
  }
  __syncthreads();   // newV/xsm stable; eps/mean/cov dead -> dx may now alias

  // ---- P2: dual-path signatures (barrier-free; dx is wave-private) ----
  const int la = l >> 4, lb = (l >> 2) & 3, lc = l & 3;
  float* dxb = smem + OFF_DX + w * 512;     // 62 interleaved 32B slots
  const float inv6 = 1.0f / 6.0f, inv24 = 1.0f / 24.0f;

  const int kk0 = w << 1, kk1 = kk0 | 1;    // this wave's two paths
  // build increment buffers, path-interleaved; dx[i]=p[i+1]-p[i].
  // Lane l retains slot l's 8 floats in VGPRs for readlane broadcast (R22).
  int A0 = 0, A1 = 0, A2 = 0, A3 = 0, B0 = 0, B1 = 0, B2 = 0, B3 = 0;
  if (l < 62) {
    const int m = l >> 1;
    float4 dv0, dv1;
    if ((l & 1) == 0) {
      float x0 = xsm[3 * m], x1 = xsm[3 * m + 1], x2 = xsm[3 * m + 2];
      float tw = xsm[128 + m] - xsm[96 + m];
      dv0.x = newVL[(3 * m) * 33 + kk0]     - x0;
      dv0.y = newVL[(3 * m + 1) * 33 + kk0] - x1;
      dv0.z = newVL[(3 * m + 2) * 33 + kk0] - x2;
      dv0.w = tw;
      dv1.x = newVL[(3 * m) * 33 + kk1]     - x0;
      dv1.y = newVL[(3 * m + 1) * 33 + kk1] - x1;
      dv1.z = newVL[(3 * m + 2) * 33 + kk1] - x2;
      dv1.w = tw;
    } else {
      float x0 = xsm[3 * m + 3], x1 = xsm[3 * m + 4], x2 = xsm[3 * m + 5];
      float tw = xsm[96 + m + 1] - xsm[128 + m];
      dv0.x = x0 - newVL[(3 * m) * 33 + kk0];
      dv0.y = x1 - newVL[(3 * m + 1) * 33 + kk0];
      dv0.z = x2 - newVL[(3 * m + 2) * 33 + kk0];
      dv0.w = tw;
      dv1.x = x0 - newVL[(3 * m) * 33 + kk1];
      dv1.y = x1 - newVL[(3 * m + 1) * 33 + kk1];
      dv1.z = x2 - newVL[(3 * m + 2) * 33 + kk1];
      dv1.w = tw;
    }
    float4 Av = make_float4(dv0.x, dv1.x, dv0.y, dv1.y);
    float4 Bv = make_float4(dv0.z, dv1.z, dv0.w, dv1.w);
    *(float4*)(dxb + l * 8)     = Av;   // LDS copy feeds the b64 selects
    *(float4*)(dxb + l * 8 + 4) = Bv;
    A0 = __float_as_int(Av.x); A1 = __float_as_int(Av.y);
    A2 = __float_as_int(Av.z); A3 = __float_as_int(Av.w);
    B0 = __float_as_int(Bv.x); B1 = __float_as_int(Bv.y);
    B2 = __float_as_int(Bv.z); B3 = __float_as_int(Bv.w);
  }
  // no __syncthreads: dxb is wave-private (same-wave lgkmcnt ordering)

  f2v p1a = {0.f, 0.f}, p2o = {0.f, 0.f}, p3 = {0.f, 0.f};
  f2v p4x = {0.f, 0.f}, p4y = {0.f, 0.f}, p4z = {0.f, 0.f}, p4w = {0.f, 0.f};
  const f2v kH = {0.5f, 0.5f}, k6 = {inv6, inv6}, k24 = {inv24, inv24};
  const f2v* dx2 = (const f2v*)dxb;       // f2v slot granularity (8 B)
#pragma unroll 2
  for (int i = 0; i < 62; ++i) {
    // wave-uniform slot fetch via readlane (SGPR results; no LDS-pipe use)
    f2v px = {__int_as_float(__builtin_amdgcn_readlane(A0, i)),
              __int_as_float(__builtin_amdgcn_readlane(A1, i))};
    f2v py = {__int_as_float(__builtin_amdgcn_readlane(A2, i)),
              __int_as_float(__builtin_amdgcn_readlane(A3, i))};
    f2v pz = {__int_as_float(__builtin_amdgcn_readlane(B0, i)),
              __int_as_float(__builtin_amdgcn_readlane(B1, i))};
    f2v pw = {__int_as_float(__builtin_amdgcn_readlane(B2, i)),
              __int_as_float(__builtin_amdgcn_readlane(B3, i))};
    // per-lane packed component selects: ONE b64 each (4 distinct addrs per
    // wave, 16-lane same-addr broadcast -> conflict-free)
    f2v dxa  = dx2[i * 4 + la];
    f2v dxbv = dx2[i * 4 + lb];
    f2v dxc  = dx2[i * 4 + lc];
    // packed two-path Chen step (identical formula/order to scalar version)
    f2v bcv  = pk_mul(dxbv, dxc);
    f2v i1   = pk_fma(p1a, k6, pk_mul(dxa, k24));
    f2v i2   = pk_fma(p1a, kH, pk_mul(dxa, k6));
    f2v u    = pk_mul(p2o, dxc);
    f2v cB   = pk_fma(u, kH, p3);
    f2v coef = pk_fma(i1, bcv, cB);
    p4x = pk_fma(coef, px, p4x);
    p4y = pk_fma(coef, py, p4y);
    p4z = pk_fma(coef, pz, p4z);
    p4w = pk_fma(coef, pw, p4w);
    p3  = pk_fma(i2, bcv, pk_add(u, p3));
    p2o = pk_fma(dxbv, pk_fma(dxa, kH, p1a), p2o);
    p1a = pk_add(p1a, dxa);
  }
  const float s1a0 = p1a.x, s2o0 = p2o.x, s30 = p3.x;
  const float s1a1 = p1a.y, s2o1 = p2o.y, s31 = p3.y;
  const float4 s40 = make_float4(p4x.x, p4y.x, p4z.x, p4w.x);
  const float4 s41 = make_float4(p4x.y, p4y.y, p4z.y, p4w.y);

  // ---- normalization + accumulate (path 0 first: same order as before) ----
  float acc1 = 0.f, acc2 = 0.f, acc3 = 0.f;
  float4 acc4 = make_float4(0.f, 0.f, 0.f, 0.f);
#pragma unroll 1
  for (int j = 0; j < 2; ++j) {
    float s1a = j ? s1a1 : s1a0;
    float s2o = j ? s2o1 : s2o0;
    float s3  = j ? s31 : s30;
    float4 s4 = j ? s41 : s40;
    float c4 = s4.x * s4.x + s4.y * s4.y + s4.z * s4.z + s4.w * s4.w;
    float c3v = s3 * s3;
    float c2v = s2o * s2o;    // x4-replicated: xor4..32 sums 16 distinct
    float c1v = s1a * s1a;    // x16-replicated: xor16,32 sums 4 distinct
#pragma unroll
    for (int off = 1; off < 64; off <<= 1) {
      c3v += __shfl_xor(c3v, off);
      c4  += __shfl_xor(c4, off);
    }
    c2v += __shfl_xor(c2v, 4);
    c2v += __shfl_xor(c2v, 8);
    c2v += __shfl_xor(c2v, 16);
    c2v += __shfl_xor(c2v, 32);
    c1v += __shfl_xor(c1v, 16);
    c1v += __shfl_xor(c1v, 32);
    float norm2 = 1.f + c1v + c2v + c3v + c4;
    float lam, lam2;
    if (norm2 <= 4.0f) {          // wave-uniform: phi(x)=x -> lam -> 1
      lam = 1.0f; lam2 = 1.0f;
    } else {
      // bisection on the quartic in m2 = lam^2 (25 iters ~ 3e-8 interval)
      float psi = 8.0f - 16.0f / norm2;
      float lo = 0.f, hi = 1.f;
#pragma unroll
      for (int it = 0; it < 25; ++it) {
        float mid = 0.5f * (lo + hi);
        float m2 = mid * mid;
        float val =
            fmaf(m2, fmaf(m2, fmaf(m2, fmaf(m2, c4, c3v), c2v), c1v), 1.f);
        bool pos = val > psi;
        hi = pos ? mid : hi;
        lo = pos ? lo : mid;
      }
      lam = 0.5f * (lo + hi);
      lam2 = lam * lam;
    }
    const float lam3 = lam2 * lam, lam4 = lam2 * lam2;
    acc1 = fmaf(s1a, lam, acc1);
    acc2 = fmaf(s2o, lam2, acc2);
    acc3 = fmaf(s3, lam3, acc3);
    acc4.x = fmaf(s4.x, lam4, acc4.x);
    acc4.y = fmaf(s4.y, lam4, acc4.y);
    acc4.z = fmaf(s4.z, lam4, acc4.z);
    acc4.w = fmaf(s4.w, lam4, acc4.w);
  }

  // ---- P3: barrier (part aliases dx), reduce waves -> sig in LDS ----
  __syncthreads();   // all waves done with dx before part overwrites it
  {
    float* part = smem + OFF_PART + w * SIGDIMc;
    if ((l & 15) == 0) part[l >> 4] = acc1;        // S1[0..3]
    if (lc == 0)       part[4 + (l >> 2)] = acc2;  // S2[0..15]
    part[20 + l] = acc3;                           // S3[0..63]
    *(float4*)(part + 84 + 4 * l) = acc4;          // S4[0..255]
  }
  __syncthreads();

  if (t < SIGDIMc) {
    float s = 0.f;
#pragma unroll
    for (int ww = 0; ww < 16; ++ww) s += smem[OFF_PART + ww * SIGDIMc + t];
    sigL[t] = s * (1.0f / 64.0f);     // this half-batch's sig contribution
  }
  __syncthreads();

  // ---- partial logits (linear in sig): waves 0..9, one class each ----
  if (w < NCLSc) {
    float s = 0.f;
    for (int jj = l; jj < SIGDIMc; jj += 64)
      s = fmaf(sigL[jj], Wf[w * SIGDIMc + jj], s);
#pragma unroll
    for (int off = 1; off < 64; off <<= 1) s += __shfl_xor(s, off);
    if (l == 0) atomicAdd(&g_logits[b * NCLSc + w], s);   // device-scope
  }
  __syncthreads();   // barrier drain (vmcnt 0) -> logit atomics complete

  // ---- last-arriving block finishes the batch (fence-free) ----
  if (t == 0) finFlag = atomicAdd(&g_cnt[b], 1);
  __syncthreads();
  if (finFlag == 1 && w == 0) {
    float lg = -1e30f;
    if (l < NCLSc)   // coherent read of the completed sum
      lg = atomicAdd(&g_logits[b * NCLSc + l], 0.0f) + bf[l];
    float mx = lg;
#pragma unroll
    for (int i2 = 0; i2 < NCLSc; ++i2) mx = fmaxf(mx, __shfl(lg, i2));
    float se = 0.f;
#pragma unroll
    for (int i2 = 0; i2 < NCLSc; ++i2) se += expf(__shfl(lg, i2) - mx);
    if (l < NCLSc) {
      out[b * NCLSc + l] = lg - mx - logf(se);
      atomicExch(&g_logits[b * NCLSc + l], 0.0f);  // coherent reset
    }
    if (l == 0) atomicExch(&g_cnt[b], 0);          // coherent reset
  }
}

extern "C" void kernel_launch(void* const* d_in, const int* in_sizes, int n_in,
                              void* d_out, int out_size, void* d_ws, size_t ws_size,
                              hipStream_t stream) {
  (void)in_sizes; (void)n_in; (void)out_size; (void)d_ws; (void)ws_size;
  const float* x   = (const float*)d_in[0];
  const float* Wm  = (const float*)d_in[1];
  const float* bm  = (const float*)d_in[2];
  const float* Wc  = (const float*)d_in[3];
  const float* bcv = (const float*)d_in[4];
  const float* Wf  = (const float*)d_in[5];
  const float* bf  = (const float*)d_in[6];
  const float* eps = (const float*)d_in[7];
  // d_in[8]/d_in[9] (x_idx/y_idx) are compile-time deterministic; hard-coded.
  float* out = (float*)d_out;

  gemm_mc<<<dim3(96, 8), 256, 0, stream>>>(x, Wm, bm, Wc, bcv);
  path_sig<<<dim3(512), 1024, 0, stream>>>(x, eps, Wf, bf, out);
}

// Round 10
// 145.419 us; speedup vs baseline: 1.3639x; 1.0501x over previous
//
#include <hip/hip_runtime.h>
#include <math.h>

// Problem constants (fixed by the reference)
namespace {
constexpr int IN_DIMc = 159;   // L1*(DIM+1)+L2
constexpr int MDIMc   = 93;    // L2*DIM
constexpr int MATELc  = 2976;  // banded tril nnz
constexpr int ROWS    = MDIMc + MATELc;  // 3069
constexpr int SIGDIMc = 340;   // 4+16+64+256
constexpr int NCLSc   = 10;
}

// Packed-FP32 helpers. R17: native IR, NOT inline asm. R19/R21/R22/R23: ALL
// four attempts to move P2's selects off the LDS pipe regressed (R2/R5 VALU
// cndmask, R8 one-hot spill, R9 readlane glue+conflicts). P2 is frozen at
// the R4/R7 form: 2 uniform b128 + 3 per-lane b64 + native pk.
typedef float f2v __attribute__((ext_vector_type(2)));
__device__ __forceinline__ f2v pk_fma(f2v a, f2v b, f2v c) {
#if __has_builtin(__builtin_elementwise_fma)
  return __builtin_elementwise_fma(a, b, c);
#else
  f2v d; d.x = fmaf(a.x, b.x, c.x); d.y = fmaf(a.y, b.y, c.y); return d;
#endif
}
__device__ __forceinline__ f2v pk_mul(f2v a, f2v b) { return a * b; }
__device__ __forceinline__ f2v pk_add(f2v a, f2v b) { return a + b; }

// Device-global scratch (static: no ws_size assumption).
__device__ float g_mc[256 * 3072];      // [B][3069] mean|cov
__device__ float g_logits[256 * NCLSc]; // per-batch logit accumulators
__device__ int   g_cnt[256];            // per-batch arrival tickets

// --------------------------------------------------------------------------
// Kernel 1: g_mc[b][r] = dot(x[b,:159], Wcat[r,:159]) + bcat[r]
// R19 geometry. Frozen (total - path_sig ~= 92us constant -> not a lever).
// --------------------------------------------------------------------------
__global__ __launch_bounds__(256) void gemm_mc(
    const float* __restrict__ x, const float* __restrict__ Wm,
    const float* __restrict__ bm, const float* __restrict__ Wc,
    const float* __restrict__ bc)
{
  __shared__ __align__(16) float wls[32 * 164];  // [row][164], cols 159..163 = 0
  __shared__ __align__(16) float xls[32 * 160];  // [batch][160]
  const int t  = threadIdx.x;
  const int r0 = blockIdx.x * 32;
  const int b0 = blockIdx.y * 32;

  for (int idx = t; idx < 32 * 164; idx += 256) {
    int rr = idx / 164, ii = idx - rr * 164;
    int r = r0 + rr;
    float v = 0.0f;
    if (ii < IN_DIMc) {
      if (r < MDIMc)      v = Wm[r * IN_DIMc + ii];
      else if (r < ROWS)  v = Wc[(r - MDIMc) * IN_DIMc + ii];
    }
    wls[idx] = v;
  }
  // x tile: global range [b0*159, (b0+32)*159) is contiguous -> coalesced.
  for (int idx = t; idx < 32 * IN_DIMc; idx += 256) {
    int bb = idx / IN_DIMc, ii = idx - bb * IN_DIMc;
    xls[bb * 160 + ii] = x[b0 * IN_DIMc + idx];
  }
  __syncthreads();

  const int rl = t & 31;    // row within tile
  const int bg = t >> 5;    // 8 groups x 4 batches
  const float* xb = xls + (bg * 4) * 160;

  float acc[4] = {0, 0, 0, 0};
  const float4* wls4 = (const float4*)wls;
  for (int c = 0; c < 39; ++c) {          // i = 0..155
    float4 wv = wls4[rl * 41 + c];
#pragma unroll
    for (int j = 0; j < 4; ++j) {
      float4 xv = *(const float4*)(xb + j * 160 + c * 4);  // broadcast b128
      acc[j] = fmaf(wv.x, xv.x, acc[j]);
      acc[j] = fmaf(wv.y, xv.y, acc[j]);
      acc[j] = fmaf(wv.z, xv.z, acc[j]);
      acc[j] = fmaf(wv.w, xv.w, acc[j]);
    }
  }
  for (int i = 156; i < IN_DIMc; ++i) {   // epilogue
    float wv = wls[rl * 164 + i];
#pragma unroll
    for (int j = 0; j < 4; ++j) acc[j] = fmaf(wv, xb[j * 160 + i], acc[j]);
  }

  const int r = r0 + rl;
  if (r < ROWS) {
    float bias = (r < MDIMc) ? bm[r] : bc[r - MDIMc];
#pragma unroll
    for (int j = 0; j < 4; ++j)
      g_mc[(size_t)(b0 + bg * 4 + j) * ROWS + r] = acc[j] + bias;
  }
}

// --------------------------------------------------------------------------
// Kernel 2: 512 blocks (2 per batch), 1024 threads = 16 waves.
// Block bx handles batch b = bx>>1, paths [h*32, h*32+32) with h = bx&1.
// ~45.7 KB LDS -> 2 blocks/CU -> 32 waves/CU (HW cap).
// R21 ledger (per-CU LDS pipe, 32 waves): LDS-throughput bound.
//  P0: stage x, mean, cov (R19 latency-overlapped), 32 eps columns.
//  P1 (R23): same-tr row pairing. Old pairing (r,r+1) mixed tr across the
//      two half-waves -> issued max(tr)+1 ~ 2.67 reads/type/y and the
//      per-lane guards blocked ds_read2 merging. New: work item q = w+16k
//      gives p=q/3, tr=q%3 (WAVE-UNIFORM -> scalar 3-way branch); half h2
//      takes triple T=2p+h2, row r=3T+tr. Bodies have unconditional
//      adjacent reads: cov[base..base+tr] and eps[ey], ey+32(, +64) ->
//      ds_read2_b32 merges. LDS ops 3925 -> 2176/block (-45%); per-lane
//      fmaf chain (y=0..T, same recurrence/order) -> bit-identical.
//  P2 (R4/R7-frozen): 2 uniform b128 + 3 per-lane b64 selects + 17 native
//      pk ops. Four VALU-select attempts regressed; do not revisit.
//  P3: reduce 16 waves -> sig[340]; waves 0..9 atomicAdd partial logits;
//      ticket on g_cnt[b]; second block's wave 0 finishes log_softmax.
// Lane layout: l = a*16+b*4+c. Lane holds S4[4l..4l+3], S3[l],
// S2[l>>2] (x4 replicated), S1[l>>4] (x16 replicated).
// --------------------------------------------------------------------------
__global__ __launch_bounds__(1024, 8) void path_sig(
    const float* __restrict__ x, const float* __restrict__ eps,
    const float* __restrict__ Wf, const float* __restrict__ bf,
    float* __restrict__ out)
{
  constexpr int OFF_XS   = 0;
  constexpr int OFF_NEWV = 160;
  constexpr int OFF_SIG  = 160;     // aliases dead newV
  constexpr int OFF_DX   = 3232;
  constexpr int OFF_EPS  = 3232;
  constexpr int OFF_MEAN = 6208;
  constexpr int OFF_COV  = 6304;    // 16B-aligned; dead before dx build
  constexpr int OFF_PART = 3232;
  __shared__ __align__(16) float smem[11424];
  __shared__ int finFlag;
  float* xsm   = smem + OFF_XS;
  float* newVL = smem + OFF_NEWV;
  float* epsL  = smem + OFF_EPS;
  float* meanL = smem + OFF_MEAN;
  float* covL  = smem + OFF_COV;
  float* sigL  = smem + OFF_SIG;

  const int t  = threadIdx.x;
  const int bx = blockIdx.x;
  const int b  = bx >> 1;
  const int h  = bx & 1;

  // ---- P0: stage inputs ----
  if (t < IN_DIMc) xsm[t] = x[b * IN_DIMc + t];
  else if (t >= 512 && t < 512 + MDIMc)
    meanL[t - 512] = g_mc[(size_t)b * ROWS + (t - 512)];
  {
    // this block's 32 eps columns: 93 rows x 8 float4
    const float4* ep4 = (const float4*)eps;
    float4* el4 = (float4*)epsL;
    if (t < 93 * 8) {
      int r = t >> 3, c4 = t & 7;
      el4[r * 8 + c4] = ep4[((size_t)b * 93 + r) * 16 + h * 8 + c4];
    }
  }
  {
    // cov[b] -> LDS: 3 rounds, loads issued before writes (latency overlap).
    // Unconditional loads stay inside g_mc even at b=255; last write guarded.
    const float* covG = g_mc + (size_t)b * ROWS + MDIMc;
    float c0 = covG[t];
    float c1 = covG[t + 1024];
    float c2 = covG[t + 2048];
    covL[t] = c0;
    covL[t + 1024] = c1;
    if (t + 2048 < MATELc) covL[t + 2048] = c2;
  }
  __syncthreads();

  // ---- P1: newV[r][col], same-tr paired halves (R23) ----
  const int l = t & 63;
  const int w = t >> 6;           // wave id 0..15
  {
    const int col = l & 31;
    const int h2  = l >> 5;
    const float* ecol = epsL + col;
#pragma unroll
    for (int k = 0; k < 3; ++k) {
      const int q  = w + (k << 4);        // 0..47, wave-uniform
      const int p  = q / 3;               // pair index (wave-uniform)
      const int tr = q - p * 3;           // wave-uniform -> scalar branch
      const int T  = (p << 1) + h2;       // this half's triple (= X)
      if (T <= 30) {
        const int r  = 3 * T + tr;
        const int tb = (tr * (tr + 1)) >> 1;
        float acc = meanL[r];
        // base(y) with X=T; recurrence base += 6*(T-y)-186
        int base = 6 * (31 * T - ((T * (T - 1)) >> 1)) + tb;
        int dlt  = 6 * T - 186;
        int ey   = 0;
        if (tr == 0) {
          for (int y = 0; y <= T; ++y) {
            acc = fmaf(covL[base], ecol[ey], acc);
            base += dlt; dlt -= 6; ey += 96;
          }
        } else if (tr == 1) {
          for (int y = 0; y <= T; ++y) {
            acc = fmaf(covL[base],     ecol[ey],      acc);
            acc = fmaf(covL[base + 1], ecol[ey + 32], acc);
            base += dlt; dlt -= 6; ey += 96;
          }
        } else {
          for (int y = 0; y <= T; ++y) {
            acc = fmaf(covL[base],     ecol[ey],      acc);
            acc = fmaf(covL[base + 1], ecol[ey + 32], acc);
            acc = fmaf(covL[base + 2], ecol[ey + 64], acc);
            base += dlt; dlt -= 6; ey += 96;
          }
        }
        newVL[r * 33 + col] = acc;
      }
    }
  }
  __syncthreads();   // newV/xsm stable; eps/mean/cov dead -> dx may now alias

  // ---- P2: dual-path signatures (barrier-free; dx is wave-private) ----
  const int la = l >> 4, lb = (l >> 2) & 3, lc = l & 3;
  float* dxb = smem + OFF_DX + w * 512;     // 62 interleaved 32B slots
  const float inv6 = 1.0f / 6.0f, inv24 = 1.0f / 24.0f;

  const int kk0 = w << 1, kk1 = kk0 | 1;    // this wave's two paths
  // build increment buffers, path-interleaved; dx[i]=p[i+1]-p[i]
  if (l < 62) {
    const int m = l >> 1;
    float4 dv0, dv1;
    if ((l & 1) == 0) {
      float x0 = xsm[3 * m], x1 = xsm[3 * m + 1], x2 = xsm[3 * m + 2];
      float tw = xsm[128 + m] - xsm[96 + m];
      dv0.x = newVL[(3 * m) * 33 + kk0]     - x0;
      dv0.y = newVL[(3 * m + 1) * 33 + kk0] - x1;
      dv0.z = newVL[(3 * m + 2) * 33 + kk0] - x2;
      dv0.w = tw;
      dv1.x = newVL[(3 * m) * 33 + kk1]     - x0;
      dv1.y = newVL[(3 * m + 1) * 33 + kk1] - x1;
      dv1.z = newVL[(3 * m + 2) * 33 + kk1] - x2;
      dv1.w = tw;
    } else {
      float x0 = xsm[3 * m + 3], x1 = xsm[3 * m + 4], x2 = xsm[3 * m + 5];
      float tw = xsm[96 + m + 1] - xsm[128 + m];
      dv0.x = x0 - newVL[(3 * m) * 33 + kk0];
      dv0.y = x1 - newVL[(3 * m + 1) * 33 + kk0];
      dv0.z = x2 - newVL[(3 * m + 2) * 33 + kk0];
      dv0.w = tw;
      dv1.x = x0 - newVL[(3 * m) * 33 + kk1];
      dv1.y = x1 - newVL[(3 * m + 1) * 33 + kk1];
      dv1.z = x2 - newVL[(3 * m + 2) * 33 + kk1];
      dv1.w = tw;
    }
    *(float4*)(dxb + l * 8)     = make_float4(dv0.x, dv1.x, dv0.y, dv1.y);
    *(float4*)(dxb + l * 8 + 4) = make_float4(dv0.z, dv1.z, dv0.w, dv1.w);
  }
  // no __syncthreads: dxb is wave-private (same-wave lgkmcnt ordering)

  f2v p1a = {0.f, 0.f}, p2o = {0.f, 0.f}, p3 = {0.f, 0.f};
  f2v p4x = {0.f, 0.f}, p4y = {0.f, 0.f}, p4z = {0.f, 0.f}, p4w = {0.f, 0.f};
  const f2v kH = {0.5f, 0.5f}, k6 = {inv6, inv6}, k24 = {inv24, inv24};
  const float4* dx4 = (const float4*)dxb;
  const f2v* dx2 = (const f2v*)dxb;       // f2v slot granularity (8 B)
#pragma unroll 4
  for (int i = 0; i < 62; ++i) {
    float4 pAv = dx4[2 * i];          // uniform b128: (d0.x,d1.x,d0.y,d1.y)
    float4 pBv = dx4[2 * i + 1];      // uniform b128: (d0.z,d1.z,d0.w,d1.w)
    f2v px = {pAv.x, pAv.y}, py = {pAv.z, pAv.w};
    f2v pz = {pBv.x, pBv.y}, pw = {pBv.z, pBv.w};
    // per-lane packed component selects: ONE b64 each (4 distinct addrs per
    // wave, 16-lane same-addr broadcast -> conflict-free)
    f2v dxa  = dx2[i * 4 + la];
    f2v dxbv = dx2[i * 4 + lb];
    f2v dxc  = dx2[i * 4 + lc];
    // packed two-path Chen step (identical formula/order to scalar version)
    f2v bcv  = pk_mul(dxbv, dxc);
    f2v i1   = pk_fma(p1a, k6, pk_mul(dxa, k24));
    f2v i2   = pk_fma(p1a, kH, pk_mul(dxa, k6));
    f2v u    = pk_mul(p2o, dxc);
    f2v cB   = pk_fma(u, kH, p3);
    f2v coef = pk_fma(i1, bcv, cB);
    p4x = pk_fma(coef, px, p4x);
    p4y = pk_fma(coef, py, p4y);
    p4z = pk_fma(coef, pz, p4z);
    p4w = pk_fma(coef, pw, p4w);
    p3  = pk_fma(i2, bcv, pk_add(u, p3));
    p2o = pk_fma(dxbv, pk_fma(dxa, kH, p1a), p2o);
    p1a = pk_add(p1a, dxa);
  }
  const float s1a0 = p1a.x, s2o0 = p2o.x, s30 = p3.x;
  const float s1a1 = p1a.y, s2o1 = p2o.y, s31 = p3.y;
  const float4 s40 = make_float4(p4x.x, p4y.x, p4z.x, p4w.x);
  const float4 s41 = make_float4(p4x.y, p4y.y, p4z.y, p4w.y);

  // ---- normalization + accumulate (path 0 first: same order as before) ----
  float acc1 = 0.f, acc2 = 0.f, acc3 = 0.f;
  float4 acc4 = make_float4(0.f, 0.f, 0.f, 0.f);
#pragma unroll 1
  for (int j = 0; j < 2; ++j) {
    float s1a = j ? s1a1 : s1a0;
    float s2o = j ? s2o1 : s2o0;
    float s3  = j ? s31 : s30;
    float4 s4 = j ? s41 : s40;
    float c4 = s4.x * s4.x + s4.y * s4.y + s4.z * s4.z + s4.w * s4.w;
    float c3v = s3 * s3;
    float c2v = s2o * s2o;    // x4-replicated: xor4..32 sums 16 distinct
    float c1v = s1a * s1a;    // x16-replicated: xor16,32 sums 4 distinct
#pragma unroll
    for (int off = 1; off < 64; off <<= 1) {
      c3v += __shfl_xor(c3v, off);
      c4  += __shfl_xor(c4, off);
    }
    c2v += __shfl_xor(c2v, 4);
    c2v += __shfl_xor(c2v, 8);
    c2v += __shfl_xor(c2v, 16);
    c2v += __shfl_xor(c2v, 32);
    c1v += __shfl_xor(c1v, 16);
    c1v += __shfl_xor(c1v, 32);
    float norm2 = 1.f + c1v + c2v + c3v + c4;
    float lam, lam2;
    if (norm2 <= 4.0f) {          // wave-uniform: phi(x)=x -> lam -> 1
      lam = 1.0f; lam2 = 1.0f;
    } else {
      // bisection on the quartic in m2 = lam^2 (25 iters ~ 3e-8 interval)
      float psi = 8.0f - 16.0f / norm2;
      float lo = 0.f, hi = 1.f;
#pragma unroll
      for (int it = 0; it < 25; ++it) {
        float mid = 0.5f * (lo + hi);
        float m2 = mid * mid;
        float val =
            fmaf(m2, fmaf(m2, fmaf(m2, fmaf(m2, c4, c3v), c2v), c1v), 1.f);
        bool pos = val > psi;
        hi = pos ? mid : hi;
        lo = pos ? lo : mid;
      }
      lam = 0.5f * (lo + hi);
      lam2 = lam * lam;
    }
    const float lam3 = lam2 * lam, lam4 = lam2 * lam2;
    acc1 = fmaf(s1a, lam, acc1);
    acc2 = fmaf(s2o, lam2, acc2);
    acc3 = fmaf(s3, lam3, acc3);
    acc4.x = fmaf(s4.x, lam4, acc4.x);
    acc4.y = fmaf(s4.y, lam4, acc4.y);
    acc4.z = fmaf(s4.z, lam4, acc4.z);
    acc4.w = fmaf(s4.w, lam4, acc4.w);
  }

  // ---- P3: barrier (part aliases dx), reduce waves -> sig in LDS ----
  __syncthreads();   // all waves done with dx before part overwrites it
  {
    float* part = smem + OFF_PART + w * SIGDIMc;
    if ((l & 15) == 0) part[l >> 4] = acc1;        // S1[0..3]
    if (lc == 0)       part[4 + (l >> 2)] = acc2;  // S2[0..15]
    part[20 + l] = acc3;                           // S3[0..63]
    *(float4*)(part + 84 + 4 * l) = acc4;          // S4[0..255]
  }
  __syncthreads();

  if (t < SIGDIMc) {
    float s = 0.f;
#pragma unroll
    for (int ww = 0; ww < 16; ++ww) s += smem[OFF_PART + ww * SIGDIMc + t];
    sigL[t] = s * (1.0f / 64.0f);     // this half-batch's sig contribution
  }
  __syncthreads();

  // ---- partial logits (linear in sig): waves 0..9, one class each ----
  if (w < NCLSc) {
    float s = 0.f;
    for (int jj = l; jj < SIGDIMc; jj += 64)
      s = fmaf(sigL[jj], Wf[w * SIGDIMc + jj], s);
#pragma unroll
    for (int off = 1; off < 64; off <<= 1) s += __shfl_xor(s, off);
    if (l == 0) atomicAdd(&g_logits[b * NCLSc + w], s);   // device-scope
  }
  __syncthreads();   // barrier drain (vmcnt 0) -> logit atomics complete

  // ---- last-arriving block finishes the batch (fence-free) ----
  if (t == 0) finFlag = atomicAdd(&g_cnt[b], 1);
  __syncthreads();
  if (finFlag == 1 && w == 0) {
    float lg = -1e30f;
    if (l < NCLSc)   // coherent read of the completed sum
      lg = atomicAdd(&g_logits[b * NCLSc + l], 0.0f) + bf[l];
    float mx = lg;
#pragma unroll
    for (int i2 = 0; i2 < NCLSc; ++i2) mx = fmaxf(mx, __shfl(lg, i2));
    float se = 0.f;
#pragma unroll
    for (int i2 = 0; i2 < NCLSc; ++i2) se += expf(__shfl(lg, i2) - mx);
    if (l < NCLSc) {
      out[b * NCLSc + l] = lg - mx - logf(se);
      atomicExch(&g_logits[b * NCLSc + l], 0.0f);  // coherent reset
    }
    if (l == 0) atomicExch(&g_cnt[b], 0);          // coherent reset
  }
}

extern "C" void kernel_launch(void* const* d_in, const int* in_sizes, int n_in,
                              void* d_out, int out_size, void* d_ws, size_t ws_size,
                              hipStream_t stream) {
  (void)in_sizes; (void)n_in; (void)out_size; (void)d_ws; (void)ws_size;
  const float* x   = (const float*)d_in[0];
  const float* Wm  = (const float*)d_in[1];
  const float* bm  = (const float*)d_in[2];
  const float* Wc  = (const float*)d_in[3];
  const float* bcv = (const float*)d_in[4];
  const float* Wf  = (const float*)d_in[5];
  const float* bf  = (const float*)d_in[6];
  const float* eps = (const float*)d_in[7];
  // d_in[8]/d_in[9] (x_idx/y_idx) are compile-time deterministic; hard-coded.
  float* out = (float*)d_out;

  gemm_mc<<<dim3(96, 8), 256, 0, stream>>>(x, Wm, bm, Wc, bcv);
  path_sig<<<dim3(512), 1024, 0, stream>>>(x, eps, Wf, bf, out);
}

// Round 13
// 138.893 us; speedup vs baseline: 1.4280x; 1.0470x over previous
//
#include <hip/hip_runtime.h>
#include <math.h>

// Problem constants (fixed by the reference)
namespace {
constexpr int IN_DIMc = 159;   // L1*(DIM+1)+L2
constexpr int MDIMc   = 93;    // L2*DIM
constexpr int MATELc  = 2976;  // banded tril nnz
constexpr int ROWS    = MDIMc + MATELc;  // 3069
constexpr int SIGDIMc = 340;   // 4+16+64+256
constexpr int NCLSc   = 10;
}

// Packed-FP32 helpers. R17: native IR, NOT inline asm. R19/R21/R22/R23: ALL
// four attempts to move P2's selects off the LDS pipe regressed (R2/R5 VALU
// cndmask, R8 one-hot spill, R9 readlane glue+conflicts). P2 is frozen at
// the R4/R7 form: 2 uniform b128 + 3 per-lane b64 + native pk.
typedef float f2v __attribute__((ext_vector_type(2)));
__device__ __forceinline__ f2v pk_fma(f2v a, f2v b, f2v c) {
#if __has_builtin(__builtin_elementwise_fma)
  return __builtin_elementwise_fma(a, b, c);
#else
  f2v d; d.x = fmaf(a.x, b.x, c.x); d.y = fmaf(a.y, b.y, c.y); return d;
#endif
}
__device__ __forceinline__ f2v pk_mul(f2v a, f2v b) { return a * b; }
__device__ __forceinline__ f2v pk_add(f2v a, f2v b) { return a + b; }

// Device-global scratch (static: no ws_size assumption).
__device__ float g_mc[256 * 3072];      // [B][3069] mean|cov
__device__ float g_logits[256 * NCLSc]; // per-batch logit accumulators
__device__ int   g_cnt[256];            // per-batch arrival tickets

// --------------------------------------------------------------------------
// Kernel 1: g_mc[b][r] = dot(x[b,:159], Wcat[r,:159]) + bcat[r]
// R19 geometry. Frozen (total - path_sig ~= 92us constant -> not a lever).
// --------------------------------------------------------------------------
__global__ __launch_bounds__(256) void gemm_mc(
    const float* __restrict__ x, const float* __restrict__ Wm,
    const float* __restrict__ bm, const float* __restrict__ Wc,
    const float* __restrict__ bc)
{
  __shared__ __align__(16) float wls[32 * 164];  // [row][164], cols 159..163 = 0
  __shared__ __align__(16) float xls[32 * 160];  // [batch][160]
  const int t  = threadIdx.x;
  const int r0 = blockIdx.x * 32;
  const int b0 = blockIdx.y * 32;

  for (int idx = t; idx < 32 * 164; idx += 256) {
    int rr = idx / 164, ii = idx - rr * 164;
    int r = r0 + rr;
    float v = 0.0f;
    if (ii < IN_DIMc) {
      if (r < MDIMc)      v = Wm[r * IN_DIMc + ii];
      else if (r < ROWS)  v = Wc[(r - MDIMc) * IN_DIMc + ii];
    }
    wls[idx] = v;
  }
  // x tile: global range [b0*159, (b0+32)*159) is contiguous -> coalesced.
  for (int idx = t; idx < 32 * IN_DIMc; idx += 256) {
    int bb = idx / IN_DIMc, ii = idx - bb * IN_DIMc;
    xls[bb * 160 + ii] = x[b0 * IN_DIMc + idx];
  }
  __syncthreads();

  const int rl = t & 31;    // row within tile
  const int bg = t >> 5;    // 8 groups x 4 batches
  const float* xb = xls + (bg * 4) * 160;

  float acc[4] = {0, 0, 0, 0};
  const float4* wls4 = (const float4*)wls;
  for (int c = 0; c < 39; ++c) {          // i = 0..155
    float4 wv = wls4[rl * 41 + c];
#pragma unroll
    for (int j = 0; j < 4; ++j) {
      float4 xv = *(const float4*)(xb + j * 160 + c * 4);  // broadcast b128
      acc[j] = fmaf(wv.x, xv.x, acc[j]);
      acc[j] = fmaf(wv.y, xv.y, acc[j]);
      acc[j] = fmaf(wv.z, xv.z, acc[j]);
      acc[j] = fmaf(wv.w, xv.w, acc[j]);
    }
  }
  for (int i = 156; i < IN_DIMc; ++i) {   // epilogue
    float wv = wls[rl * 164 + i];
#pragma unroll
    for (int j = 0; j < 4; ++j) acc[j] = fmaf(wv, xb[j * 160 + i], acc[j]);
  }

  const int r = r0 + rl;
  if (r < ROWS) {
    float bias = (r < MDIMc) ? bm[r] : bc[r - MDIMc];
#pragma unroll
    for (int j = 0; j < 4; ++j)
      g_mc[(size_t)(b0 + bg * 4 + j) * ROWS + r] = acc[j] + bias;
  }
}

// --------------------------------------------------------------------------
// Kernel 2: 512 blocks (2 per batch), 1024 threads = 16 waves.
// Block bx handles batch b = bx>>1, paths [h*32, h*32+32) with h = bx&1.
// ~46.1 KB LDS; occupancy is THREAD-limited (2x1024 = 2048 cap), so LDS has
// headroom to 80 KB -> newV padded to stride 34 for b64 column-pair reads.
// R21 ledger (per-CU LDS pipe, 32 waves): LDS-throughput bound.
//  P0: stage x, mean, cov (R19 latency-overlapped), 32 eps columns.
//  P1 (R24): 4 row-groups x 2-col f2v lanes. Lane (g=l>>4, cp=l&15) handles
//      row r=3(4p'+g)+tr, cols {2cp,2cp+1}; (tr,p') wave-uniform (24 items
//      on 16 waves, q=w+16k<24). eps addresses are g-independent -> shared
//      across groups; eps read as ONE b64/pair (newV stride 34 keeps writes
//      8B-aligned); cov b32 broadcast (4 addrs/wave). LDS ops 2176 -> 1152
//      per block (-47%). Same y/tc fmaf order per column -> bit-identical.
//  P2 (R4/R7-frozen): 2 uniform b128 + 3 per-lane b64 selects + 17 native
//      pk ops. Four VALU-select attempts regressed; do not revisit.
//  P3: reduce 16 waves -> sig[340]; waves 0..9 atomicAdd partial logits;
//      ticket on g_cnt[b]; second block's wave 0 finishes log_softmax.
// Lane layout (P2): l = a*16+b*4+c. Lane holds S4[4l..4l+3], S3[l],
// S2[l>>2] (x4 replicated), S1[l>>4] (x16 replicated).
// (R26: third submission of R24 byte-identical -- R11/R12 failures had NO
//  timing block = container-acquire-stage infra failure, kernel never ran.
//  Audit: no LDS OOB, no UB, no divergent barriers, all f2v 8B-aligned.
//  If this fails again, next round submits the R10-proven kernel as a
//  discriminator.)
// --------------------------------------------------------------------------
__global__ __launch_bounds__(1024, 8) void path_sig(
    const float* __restrict__ x, const float* __restrict__ eps,
    const float* __restrict__ Wf, const float* __restrict__ bf,
    float* __restrict__ out)
{
  // LDS (floats), total 11,520 = 46,080 B (+4 B flag); 2 blocks/CU.
  //  [0,160)        xsm (live all phases)
  //  [160,3322)     newV 93x34 (live P1..dx build); sig[340] reuses
  //                 [160,500) after dx build (newV dead)
  //  [3328,11520)   dx: 16 waves x 512 floats (live P2; path-interleaved)
  //    aliases: eps [3328,6304) + mean [6304,6397) + cov [6400,9376)
  //             (all dead after P1); part [3328,8768) (post-barrier)
  constexpr int OFF_XS   = 0;
  constexpr int OFF_NEWV = 160;
  constexpr int OFF_SIG  = 160;     // aliases dead newV
  constexpr int OFF_DX   = 3328;
  constexpr int OFF_EPS  = 3328;
  constexpr int OFF_MEAN = 6304;
  constexpr int OFF_COV  = 6400;    // 16B-aligned; dead before dx build
  constexpr int OFF_PART = 3328;
  __shared__ __align__(16) float smem[11520];
  __shared__ int finFlag;
  float* xsm   = smem + OFF_XS;
  float* newVL = smem + OFF_NEWV;
  float* epsL  = smem + OFF_EPS;
  float* meanL = smem + OFF_MEAN;
  float* covL  = smem + OFF_COV;
  float* sigL  = smem + OFF_SIG;

  const int t  = threadIdx.x;
  const int bx = blockIdx.x;
  const int b  = bx >> 1;
  const int h  = bx & 1;

  // ---- P0: stage inputs ----
  if (t < IN_DIMc) xsm[t] = x[b * IN_DIMc + t];
  else if (t >= 512 && t < 512 + MDIMc)
    meanL[t - 512] = g_mc[(size_t)b * ROWS + (t - 512)];
  {
    // this block's 32 eps columns: 93 rows x 8 float4
    const float4* ep4 = (const float4*)eps;
    float4* el4 = (float4*)epsL;
    if (t < 93 * 8) {
      int r = t >> 3, c4 = t & 7;
      el4[r * 8 + c4] = ep4[((size_t)b * 93 + r) * 16 + h * 8 + c4];
    }
  }
  {
    // cov[b] -> LDS: 3 rounds, loads issued before writes (latency overlap).
    // Unconditional loads stay inside g_mc even at b=255; last write guarded.
    const float* covG = g_mc + (size_t)b * ROWS + MDIMc;
    float c0 = covG[t];
    float c1 = covG[t + 1024];
    float c2 = covG[t + 2048];
    covL[t] = c0;
    covL[t + 1024] = c1;
    if (t + 2048 < MATELc) covL[t + 2048] = c2;
  }
  __syncthreads();

  // ---- P1 (R24): newV[r][2cp..2cp+1], 4 same-tr row-groups per wave ----
  const int l = t & 63;
  const int w = t >> 6;           // wave id 0..15
  {
    const int cp = l & 15;        // column pair -> cols 2cp, 2cp+1
    const int g  = l >> 4;        // row-group 0..3
    const float* ep2 = epsL + 2 * cp;
#pragma unroll
    for (int k = 0; k < 2; ++k) {
      const int q = w + (k << 4);         // 0..31, wave-uniform
      if (q < 24) {
        const int p2 = q / 3;             // p' (wave-uniform)
        const int tr = q - p2 * 3;        // wave-uniform -> scalar branch
        const int Tmax = (p2 == 7) ? 30 : ((p2 << 2) + 3);
        int T = (p2 << 2) + g;            // this lane's triple (= X)
        if (T > 30) T = -1;               // invalid lane: never active
        const int r  = 3 * T + tr;
        const int tb = (tr * (tr + 1)) >> 1;
        f2v acc;
        acc.x = (T >= 0) ? meanL[r] : 0.f;
        acc.y = acc.x;
        // base(y) with X=T; recurrence base += 6*(T-y)-186
        int base = 6 * (31 * T - ((T * (T - 1)) >> 1)) + tb;
        int dlt  = 6 * T - 186;
        if (tr == 0) {
          for (int y = 0; y <= Tmax; ++y) {
            if (y <= T) {
              float cv0 = covL[base];
              f2v e0 = *(const f2v*)(ep2 + 96 * y);
              acc.x = fmaf(cv0, e0.x, acc.x);
              acc.y = fmaf(cv0, e0.y, acc.y);
              base += dlt; dlt -= 6;
            }
          }
        } else if (tr == 1) {
          for (int y = 0; y <= Tmax; ++y) {
            if (y <= T) {
              float cv0 = covL[base], cv1 = covL[base + 1];
              f2v e0 = *(const f2v*)(ep2 + 96 * y);
              f2v e1 = *(const f2v*)(ep2 + 96 * y + 32);
              acc.x = fmaf(cv0, e0.x, acc.x);
              acc.y = fmaf(cv0, e0.y, acc.y);
              acc.x = fmaf(cv1, e1.x, acc.x);
              acc.y = fmaf(cv1, e1.y, acc.y);
              base += dlt; dlt -= 6;
            }
          }
        } else {
          for (int y = 0; y <= Tmax; ++y) {
            if (y <= T) {
              float cv0 = covL[base], cv1 = covL[base + 1], cv2 = covL[base + 2];
              f2v e0 = *(const f2v*)(ep2 + 96 * y);
              f2v e1 = *(const f2v*)(ep2 + 96 * y + 32);
              f2v e2 = *(const f2v*)(ep2 + 96 * y + 64);
              acc.x = fmaf(cv0, e0.x, acc.x);
              acc.y = fmaf(cv0, e0.y, acc.y);
              acc.x = fmaf(cv1, e1.x, acc.x);
              acc.y = fmaf(cv1, e1.y, acc.y);
              acc.x = fmaf(cv2, e2.x, acc.x);
              acc.y = fmaf(cv2, e2.y, acc.y);
              base += dlt; dlt -= 6;
            }
          }
        }
        if (T >= 0) *(f2v*)(newVL + r * 34 + 2 * cp) = acc;
      }
    }
  }
  __syncthreads();   // newV/xsm stable; eps/mean/cov dead -> dx may now alias

  // ---- P2: dual-path signatures (barrier-free; dx is wave-private) ----
  const int la = l >> 4, lb = (l >> 2) & 3, lc = l & 3;
  float* dxb = smem + OFF_DX + w * 512;     // 62 interleaved 32B slots
  const float inv6 = 1.0f / 6.0f, inv24 = 1.0f / 24.0f;

  const int kk0 = w << 1, kk1 = kk0 | 1;    // this wave's two paths
  // build increment buffers, path-interleaved; dx[i]=p[i+1]-p[i]
  if (l < 62) {
    const int m = l >> 1;
    float4 dv0, dv1;
    if ((l & 1) == 0) {
      float x0 = xsm[3 * m], x1 = xsm[3 * m + 1], x2 = xsm[3 * m + 2];
      float tw = xsm[128 + m] - xsm[96 + m];
      dv0.x = newVL[(3 * m) * 34 + kk0]     - x0;
      dv0.y = newVL[(3 * m + 1) * 34 + kk0] - x1;
      dv0.z = newVL[(3 * m + 2) * 34 + kk0] - x2;
      dv0.w = tw;
      dv1.x = newVL[(3 * m) * 34 + kk1]     - x0;
      dv1.y = newVL[(3 * m + 1) * 34 + kk1] - x1;
      dv1.z = newVL[(3 * m + 2) * 34 + kk1] - x2;
      dv1.w = tw;
    } else {
      float x0 = xsm[3 * m + 3], x1 = xsm[3 * m + 4], x2 = xsm[3 * m + 5];
      float tw = xsm[96 + m + 1] - xsm[128 + m];
      dv0.x = x0 - newVL[(3 * m) * 34 + kk0];
      dv0.y = x1 - newVL[(3 * m + 1) * 34 + kk0];
      dv0.z = x2 - newVL[(3 * m + 2) * 34 + kk0];
      dv0.w = tw;
      dv1.x = x0 - newVL[(3 * m) * 34 + kk1];
      dv1.y = x1 - newVL[(3 * m + 1) * 34 + kk1];
      dv1.z = x2 - newVL[(3 * m + 2) * 34 + kk1];
      dv1.w = tw;
    }
    *(float4*)(dxb + l * 8)     = make_float4(dv0.x, dv1.x, dv0.y, dv1.y);
    *(float4*)(dxb + l * 8 + 4) = make_float4(dv0.z, dv1.z, dv0.w, dv1.w);
  }
  // no __syncthreads: dxb is wave-private (same-wave lgkmcnt ordering)

  f2v p1a = {0.f, 0.f}, p2o = {0.f, 0.f}, p3 = {0.f, 0.f};
  f2v p4x = {0.f, 0.f}, p4y = {0.f, 0.f}, p4z = {0.f, 0.f}, p4w = {0.f, 0.f};
  const f2v kH = {0.5f, 0.5f}, k6 = {inv6, inv6}, k24 = {inv24, inv24};
  const float4* dx4 = (const float4*)dxb;
  const f2v* dx2 = (const f2v*)dxb;       // f2v slot granularity (8 B)
#pragma unroll 4
  for (int i = 0; i < 62; ++i) {
    float4 pAv = dx4[2 * i];          // uniform b128: (d0.x,d1.x,d0.y,d1.y)
    float4 pBv = dx4[2 * i + 1];      // uniform b128: (d0.z,d1.z,d0.w,d1.w)
    f2v px = {pAv.x, pAv.y}, py = {pAv.z, pAv.w};
    f2v pz = {pBv.x, pBv.y}, pw = {pBv.z, pBv.w};
    // per-lane packed component selects: ONE b64 each (4 distinct addrs per
    // wave, 16-lane same-addr broadcast -> conflict-free)
    f2v dxa  = dx2[i * 4 + la];
    f2v dxbv = dx2[i * 4 + lb];
    f2v dxc  = dx2[i * 4 + lc];
    // packed two-path Chen step (identical formula/order to scalar version)
    f2v bcv  = pk_mul(dxbv, dxc);
    f2v i1   = pk_fma(p1a, k6, pk_mul(dxa, k24));
    f2v i2   = pk_fma(p1a, kH, pk_mul(dxa, k6));
    f2v u    = pk_mul(p2o, dxc);
    f2v cB   = pk_fma(u, kH, p3);
    f2v coef = pk_fma(i1, bcv, cB);
    p4x = pk_fma(coef, px, p4x);
    p4y = pk_fma(coef, py, p4y);
    p4z = pk_fma(coef, pz, p4z);
    p4w = pk_fma(coef, pw, p4w);
    p3  = pk_fma(i2, bcv, pk_add(u, p3));
    p2o = pk_fma(dxbv, pk_fma(dxa, kH, p1a), p2o);
    p1a = pk_add(p1a, dxa);
  }
  const float s1a0 = p1a.x, s2o0 = p2o.x, s30 = p3.x;
  const float s1a1 = p1a.y, s2o1 = p2o.y, s31 = p3.y;
  const float4 s40 = make_float4(p4x.x, p4y.x, p4z.x, p4w.x);
  const float4 s41 = make_float4(p4x.y, p4y.y, p4z.y, p4w.y);

  // ---- normalization + accumulate (path 0 first: same order as before) ----
  float acc1 = 0.f, acc2 = 0.f, acc3 = 0.f;
  float4 acc4 = make_float4(0.f, 0.f, 0.f, 0.f);
#pragma unroll 1
  for (int j = 0; j < 2; ++j) {
    float s1a = j ? s1a1 : s1a0;
    float s2o = j ? s2o1 : s2o0;
    float s3  = j ? s31 : s30;
    float4 s4 = j ? s41 : s40;
    float c4 = s4.x * s4.x + s4.y * s4.y + s4.z * s4.z + s4.w * s4.w;
    float c3v = s3 * s3;
    float c2v = s2o * s2o;    // x4-replicated: xor4..32 sums 16 distinct
    float c1v = s1a * s1a;    // x16-replicated: xor16,32 sums 4 distinct
#pragma unroll
    for (int off = 1; off < 64; off <<= 1) {
      c3v += __shfl_xor(c3v, off);
      c4  += __shfl_xor(c4, off);
    }
    c2v += __shfl_xor(c2v, 4);
    c2v += __shfl_xor(c2v, 8);
    c2v += __shfl_xor(c2v, 16);
    c2v += __shfl_xor(c2v, 32);
    c1v += __shfl_xor(c1v, 16);
    c1v += __shfl_xor(c1v, 32);
    float norm2 = 1.f + c1v + c2v + c3v + c4;
    float lam, lam2;
    if (norm2 <= 4.0f) {          // wave-uniform: phi(x)=x -> lam -> 1
      lam = 1.0f; lam2 = 1.0f;
    } else {
      // bisection on the quartic in m2 = lam^2 (25 iters ~ 3e-8 interval)
      float psi = 8.0f - 16.0f / norm2;
      float lo = 0.f, hi = 1.f;
#pragma unroll
      for (int it = 0; it < 25; ++it) {
        float mid = 0.5f * (lo + hi);
        float m2 = mid * mid;
        float val =
            fmaf(m2, fmaf(m2, fmaf(m2, fmaf(m2, c4, c3v), c2v), c1v), 1.f);
        bool pos = val > psi;
        hi = pos ? mid : hi;
        lo = pos ? lo : mid;
      }
      lam = 0.5f * (lo + hi);
      lam2 = lam * lam;
    }
    const float lam3 = lam2 * lam, lam4 = lam2 * lam2;
    acc1 = fmaf(s1a, lam, acc1);
    acc2 = fmaf(s2o, lam2, acc2);
    acc3 = fmaf(s3, lam3, acc3);
    acc4.x = fmaf(s4.x, lam4, acc4.x);
    acc4.y = fmaf(s4.y, lam4, acc4.y);
    acc4.z = fmaf(s4.z, lam4, acc4.z);
    acc4.w = fmaf(s4.w, lam4, acc4.w);
  }

  // ---- P3: barrier (part aliases dx), reduce waves -> sig in LDS ----
  __syncthreads();   // all waves done with dx before part overwrites it
  {
    float* part = smem + OFF_PART + w * SIGDIMc;
    if ((l & 15) == 0) part[l >> 4] = acc1;        // S1[0..3]
    if (lc == 0)       part[4 + (l >> 2)] = acc2;  // S2[0..15]
    part[20 + l] = acc3;                           // S3[0..63]
    *(float4*)(part + 84 + 4 * l) = acc4;          // S4[0..255]
  }
  __syncthreads();

  if (t < SIGDIMc) {
    float s = 0.f;
#pragma unroll
    for (int ww = 0; ww < 16; ++ww) s += smem[OFF_PART + ww * SIGDIMc + t];
    sigL[t] = s * (1.0f / 64.0f);     // this half-batch's sig contribution
  }
  __syncthreads();

  // ---- partial logits (linear in sig): waves 0..9, one class each ----
  if (w < NCLSc) {
    float s = 0.f;
    for (int jj = l; jj < SIGDIMc; jj += 64)
      s = fmaf(sigL[jj], Wf[w * SIGDIMc + jj], s);
#pragma unroll
    for (int off = 1; off < 64; off <<= 1) s += __shfl_xor(s, off);
    if (l == 0) atomicAdd(&g_logits[b * NCLSc + w], s);   // device-scope
  }
  __syncthreads();   // barrier drain (vmcnt 0) -> logit atomics complete

  // ---- last-arriving block finishes the batch (fence-free) ----
  if (t == 0) finFlag = atomicAdd(&g_cnt[b], 1);
  __syncthreads();
  if (finFlag == 1 && w == 0) {
    float lg = -1e30f;
    if (l < NCLSc)   // coherent read of the completed sum
      lg = atomicAdd(&g_logits[b * NCLSc + l], 0.0f) + bf[l];
    float mx = lg;
#pragma unroll
    for (int i2 = 0; i2 < NCLSc; ++i2) mx = fmaxf(mx, __shfl(lg, i2));
    float se = 0.f;
#pragma unroll
    for (int i2 = 0; i2 < NCLSc; ++i2) se += expf(__shfl(lg, i2) - mx);
    if (l < NCLSc) {
      out[b * NCLSc + l] = lg - mx - logf(se);
      atomicExch(&g_logits[b * NCLSc + l], 0.0f);  // coherent reset
    }
    if (l == 0) atomicExch(&g_cnt[b], 0);          // coherent reset
  }
}

extern "C" void kernel_launch(void* const* d_in, const int* in_sizes, int n_in,
                              void* d_out, int out_size, void* d_ws, size_t ws_size,
                              hipStream_t stream) {
  (void)in_sizes; (void)n_in; (void)out_size; (void)d_ws; (void)ws_size;
  const float* x   = (const float*)d_in[0];
  const float* Wm  = (const float*)d_in[1];
  const float* bm  = (const float*)d_in[2];
  const float* Wc  = (const float*)d_in[3];
  const float* bcv = (const float*)d_in[4];
  const float* Wf  = (const float*)d_in[5];
  const float* bf  = (const float*)d_in[6];
  const float* eps = (const float*)d_in[7];
  // d_in[8]/d_in[9] (x_idx/y_idx) are compile-time deterministic; hard-coded.
  float* out = (float*)d_out;

  gemm_mc<<<dim3(96, 8), 256, 0, stream>>>(x, Wm, bm, Wc, bcv);
  path_sig<<<dim3(512), 1024, 0, stream>>>(x, eps, Wf, bf, out);
}